// Round 3
// baseline (177.290 us; speedup 1.0000x reference)
//
#include <hip/hip_runtime.h>

// pred_vol shape (1,1,64,512,512) fp32; threshold 0.5; window 9 (R=4)
static constexpr int Dd = 64;
static constexpr int Hh = 512;
static constexpr int Ww = 512;
static constexpr int RAD = 4;
static constexpr float THRESH_V = 0.5f;
static constexpr int NTOT = Dd * Hh * Ww;        // 16,777,216
static constexpr int W4 = Ww / 4;                // 128 float4 per row
static constexpr int PLANE4 = Hh * W4;           // 65536 float4 per D-plane

__device__ __forceinline__ float thr(float v) { return v > THRESH_V ? v : 0.0f; }

__device__ __forceinline__ float4 f4max(float4 a, float4 b) {
    return make_float4(fmaxf(a.x, b.x), fmaxf(a.y, b.y), fmaxf(a.z, b.z), fmaxf(a.w, b.w));
}
__device__ __forceinline__ float4 thr4(float4 v) {
    return make_float4(thr(v.x), thr(v.y), thr(v.z), thr(v.w));
}

// ---------------- Pass 1: threshold + max along W (x -> ws) ----------------
__global__ void wmax4_k(const float4* __restrict__ x4, float4* __restrict__ o4) {
    int idx = blockIdx.x * 256 + threadIdx.x;       // NTOT/4 threads
    int c = idx & (W4 - 1);
    int rowbase = idx - c;
    float4 v0 = x4[rowbase + (c > 0 ? c - 1 : 0)];
    float4 v1 = x4[idx];
    float4 v2 = x4[rowbase + (c < W4 - 1 ? c + 1 : W4 - 1)];
    v0 = thr4(v0); v1 = thr4(v1); v2 = thr4(v2);
    float l3 = v0.w, l2 = fmaxf(v0.z, l3), l1 = fmaxf(v0.y, l2), l0 = fmaxf(v0.x, l1);
    float core = fmaxf(fmaxf(v1.x, v1.y), fmaxf(v1.z, v1.w));
    float r8 = v2.x, r9 = fmaxf(r8, v2.y), r10 = fmaxf(r9, v2.z), r11 = fmaxf(r10, v2.w);
    float4 o;
    o.x = fmaxf(l0, fmaxf(core, r8));
    o.y = fmaxf(l1, fmaxf(core, r9));
    o.z = fmaxf(l2, fmaxf(core, r10));
    o.w = fmaxf(l3, fmaxf(core, r11));
    o4[idx] = o;
}

// ---------------- Pass 2: H-max + D-max (register ring) + compare ----------
struct HPair { float4 h0, h1; };

// H-window maxes for outputs (h0, h0+1) of plane `plane`, column c, from
// 10 clamped row offsets. Shared interior tree w[1..8] used by both.
__device__ __forceinline__ HPair hmax_pair(const float4* __restrict__ in4,
                                           int plane, const int* rowoff) {
    float4 w0 = in4[plane + rowoff[0]];
    float4 s  = in4[plane + rowoff[1]];
#pragma unroll
    for (int k = 2; k <= 8; ++k) s = f4max(s, in4[plane + rowoff[k]]);
    float4 w9 = in4[plane + rowoff[9]];
    HPair r; r.h0 = f4max(w0, s); r.h1 = f4max(s, w9); return r;
}

__global__ void hdmax_k(const float4* __restrict__ ws4, const float4* __restrict__ x4,
                        float4* __restrict__ o4) {
    int idx = blockIdx.x * 256 + threadIdx.x;   // 262144 threads
    int c  = idx & (W4 - 1);
    int hp = (idx >> 7) & 255;                  // h-pair index (512/2)
    int dc = idx >> 15;                         // d-chunk (64/8 = 8)
    int h0 = hp << 1;
    int rowoff[10];
#pragma unroll
    for (int s = 0; s < 10; ++s) {
        int h = h0 + s - RAD;
        h = h < 0 ? 0 : (h > Hh - 1 ? Hh - 1 : h);
        rowoff[s] = (h << 7) + c;
    }
    int dc0 = dc << 3;
    // ring holds HWmax for d' = dc0-4 .. dc0+3 (clamped), slots 0..7
    float4 r0[8], r1[8];
#pragma unroll
    for (int s = 0; s < 8; ++s) {
        int d = dc0 + s - RAD;
        d = d < 0 ? 0 : (d > Dd - 1 ? Dd - 1 : d);
        HPair p = hmax_pair(ws4, d * PLANE4, rowoff);
        r0[s] = p.h0; r1[s] = p.h1;
    }
#pragma unroll
    for (int j = 0; j < 8; ++j) {
        int d = dc0 + j;
        int dn = d + RAD; if (dn > Dd - 1) dn = Dd - 1;
        HPair p = hmax_pair(ws4, dn * PLANE4, rowoff);
        float4 m0 = p.h0, m1 = p.h1;
#pragma unroll
        for (int k = 0; k < 8; ++k) { m0 = f4max(m0, r0[k]); m1 = f4max(m1, r1[k]); }
        int ob = d * PLANE4 + (h0 << 7) + c;
        float4 tx0 = thr4(x4[ob]);
        float4 tx1 = thr4(x4[ob + W4]);
        float4 q0, q1;
        q0.x = (tx0.x > 0.0f && tx0.x == m0.x) ? tx0.x : 0.0f;
        q0.y = (tx0.y > 0.0f && tx0.y == m0.y) ? tx0.y : 0.0f;
        q0.z = (tx0.z > 0.0f && tx0.z == m0.z) ? tx0.z : 0.0f;
        q0.w = (tx0.w > 0.0f && tx0.w == m0.w) ? tx0.w : 0.0f;
        q1.x = (tx1.x > 0.0f && tx1.x == m1.x) ? tx1.x : 0.0f;
        q1.y = (tx1.y > 0.0f && tx1.y == m1.y) ? tx1.y : 0.0f;
        q1.z = (tx1.z > 0.0f && tx1.z == m1.z) ? tx1.z : 0.0f;
        q1.w = (tx1.w > 0.0f && tx1.w == m1.w) ? tx1.w : 0.0f;
        o4[ob] = q0;
        o4[ob + W4] = q1;
        // shift ring, push p (static indices -> SSA renaming under full unroll)
#pragma unroll
        for (int k = 0; k < 7; ++k) { r0[k] = r0[k + 1]; r1[k] = r1[k + 1]; }
        r0[7] = p.h0; r1[7] = p.h1;
    }
}

// ---------------- Fallback (ws too small): direct 9^3 scan ----------------
__global__ void naive_k(const float* __restrict__ x, float* __restrict__ o) {
    int idx = blockIdx.x * 256 + threadIdx.x;
    int w = idx & (Ww - 1);
    int h = (idx >> 9) & (Hh - 1);
    int d = idx >> 18;
    float tx = thr(x[idx]);
    if (tx <= 0.0f) { o[idx] = 0.0f; return; }
    int w0 = max(w - RAD, 0), w1 = min(w + RAD, Ww - 1);
    int h0 = max(h - RAD, 0), h1 = min(h + RAD, Hh - 1);
    int d0 = max(d - RAD, 0), d1 = min(d + RAD, Dd - 1);
    float m = 0.0f;
    for (int dd = d0; dd <= d1; ++dd)
        for (int hh = h0; hh <= h1; ++hh) {
            int base = dd * (Hh * Ww) + hh * Ww;
            for (int ww = w0; ww <= w1; ++ww)
                m = fmaxf(m, thr(x[base + ww]));
        }
    o[idx] = (tx == m) ? tx : 0.0f;
}

extern "C" void kernel_launch(void* const* d_in, const int* in_sizes, int n_in,
                              void* d_out, int out_size, void* d_ws, size_t ws_size,
                              hipStream_t stream) {
    const float* x = (const float*)d_in[0];
    float* out = (float*)d_out;
    float* ws = (float*)d_ws;

    if (ws_size >= (size_t)NTOT * sizeof(float)) {
        const float4* x4 = (const float4*)x;
        float4* out4 = (float4*)out;
        float4* ws4 = (float4*)ws;
        // pass1: x -> ws (threshold + W-max)
        wmax4_k<<<dim3(NTOT / 4 / 256), dim3(256), 0, stream>>>(x4, ws4);
        // pass2: ws + x -> out (H-max + D-max ring + local-max compare)
        hdmax_k<<<dim3(NTOT / 4 / 16 / 256), dim3(256), 0, stream>>>(ws4, x4, out4);
    } else {
        naive_k<<<dim3(NTOT / 256), dim3(256), 0, stream>>>(x, out);
    }
}

// Round 4
// 144.484 us; speedup vs baseline: 1.2271x; 1.2271x over previous
//
#include <hip/hip_runtime.h>

// pred_vol shape (1,1,64,512,512) fp32; threshold 0.5; window 9 (R=4).
// Key identity: thr is monotone => max(thr(x)) == thr(max(x)), and the window
// contains the center, so reference output == (c > 0.5 && c == max9x9x9_raw(x)) ? c : 0.
// => no thresholding needed anywhere except the final compare.
static constexpr int Dd = 64;
static constexpr int Hh = 512;
static constexpr int Ww = 512;
static constexpr int RAD = 4;
static constexpr float THRESH_V = 0.5f;
static constexpr int W4 = Ww / 4;          // 128 float4 per row
static constexpr int PLANE4 = Hh * W4;     // 65536 float4 per D-plane

static constexpr int TH = 4;               // output h-rows per block
static constexpr int DC = 16;              // output d-planes per block
static constexpr int ROWS = TH + 2 * RAD;  // 12 staged rows per plane
static constexpr int STEPS = DC + 2 * RAD; // 24 d-steps per block
static constexpr int NBLK = (Hh / TH) * (Dd / DC);  // 128 * 4 = 512 blocks

__device__ __forceinline__ float4 f4max(float4 a, float4 b) {
    return make_float4(fmaxf(a.x, b.x), fmaxf(a.y, b.y), fmaxf(a.z, b.z), fmaxf(a.w, b.w));
}

__global__ __launch_bounds__(512, 4)
void fused_nms_k(const float4* __restrict__ x4, float4* __restrict__ o4) {
    // double-buffered staging of per-plane W-max rows: 2 * 12 * 128 * 16B = 48 KB
    __shared__ float4 buf[2][ROWS * W4];

    const int tid = threadIdx.x;
    const int w4  = tid & (W4 - 1);          // 0..127
    const int hr  = tid >> 7;                // 0..3 (owned h-row within tile)
    const int ht  = blockIdx.x & (Hh / TH - 1);  // 0..127
    const int dc  = blockIdx.x >> 7;             // 0..3
    const int h0  = ht * TH;
    const int d0  = dc * DC;

    const int colm = w4 ? w4 - 1 : 0;
    const int colp = (w4 < W4 - 1) ? w4 + 1 : W4 - 1;

    // Each thread stages 3 LDS slots: slot = k*512 + tid -> row = 4k + hr, col = w4
    int rowoff[3];
#pragma unroll
    for (int k = 0; k < 3; ++k) {
        int gh = h0 - RAD + hr + 4 * k;
        gh = gh < 0 ? 0 : (gh > Hh - 1 ? Hh - 1 : gh);
        rowoff[k] = gh * W4;
    }
    const int outrow = (h0 + hr) * W4 + w4;

    const float4 z = make_float4(0.f, 0.f, 0.f, 0.f);
    float4 ring[9], xr[5];
#pragma unroll
    for (int i = 0; i < 9; ++i) ring[i] = z;
#pragma unroll
    for (int i = 0; i < 5; ++i) xr[i] = z;

    for (int t = 0; t < STEPS; ++t) {
        int gd = d0 - RAD + t;
        gd = gd < 0 ? 0 : (gd > Dd - 1 ? Dd - 1 : gd);
        const float4* pl = x4 + (size_t)gd * PLANE4;
        float4* B = buf[t & 1];

        float4 center = z;
#pragma unroll
        for (int k = 0; k < 3; ++k) {
            const float4* row = pl + rowoff[k];
            float4 v0 = row[colm], v1 = row[w4], v2 = row[colp];
            if (k == 1) center = v1;  // raw x at (gd, h0+hr, w4)
            // 9-wide W-window maxes for the 4 lanes of v1
            float l3 = v0.w, l2 = fmaxf(v0.z, l3), l1 = fmaxf(v0.y, l2), l0 = fmaxf(v0.x, l1);
            float core = fmaxf(fmaxf(v1.x, v1.y), fmaxf(v1.z, v1.w));
            float r8 = v2.x, r9 = fmaxf(r8, v2.y), r10 = fmaxf(r9, v2.z), r11 = fmaxf(r10, v2.w);
            float4 o;
            o.x = fmaxf(l0, fmaxf(core, r8));
            o.y = fmaxf(l1, fmaxf(core, r9));
            o.z = fmaxf(l2, fmaxf(core, r10));
            o.w = fmaxf(l3, fmaxf(core, r11));
            B[k * 512 + tid] = o;
        }
        __syncthreads();

        // H-max over 9 staged rows at this thread's column
        float4 m = B[hr * W4 + w4];
#pragma unroll
        for (int i = 1; i < 9; ++i) m = f4max(m, B[(hr + i) * W4 + w4]);

        // push D-ring (shift register, static indices) and center lag ring
#pragma unroll
        for (int i = 0; i < 8; ++i) ring[i] = ring[i + 1];
        ring[8] = m;
#pragma unroll
        for (int i = 0; i < 4; ++i) xr[i] = xr[i + 1];
        xr[4] = center;

        if (t >= 2 * RAD) {              // ring now holds planes d-4..d+4 (clamped)
            const int d = d0 + t - 2 * RAD;
            float4 mm = ring[0];
#pragma unroll
            for (int i = 1; i < 9; ++i) mm = f4max(mm, ring[i]);
            const float4 c = xr[0];      // raw center at plane d (lag 4)
            float4 q;
            q.x = (c.x > THRESH_V && c.x == mm.x) ? c.x : 0.0f;
            q.y = (c.y > THRESH_V && c.y == mm.y) ? c.y : 0.0f;
            q.z = (c.z > THRESH_V && c.z == mm.z) ? c.z : 0.0f;
            q.w = (c.w > THRESH_V && c.w == mm.w) ? c.w : 0.0f;
            o4[(size_t)d * PLANE4 + outrow] = q;
        }
    }
}

extern "C" void kernel_launch(void* const* d_in, const int* in_sizes, int n_in,
                              void* d_out, int out_size, void* d_ws, size_t ws_size,
                              hipStream_t stream) {
    const float4* x4 = (const float4*)d_in[0];
    float4* out4 = (float4*)d_out;
    (void)d_ws; (void)ws_size; (void)in_sizes; (void)n_in; (void)out_size;
    fused_nms_k<<<dim3(NBLK), dim3(512), 0, stream>>>(x4, out4);
}

// Round 5
// 138.380 us; speedup vs baseline: 1.2812x; 1.0441x over previous
//
#include <hip/hip_runtime.h>

// pred_vol shape (1,1,64,512,512) fp32; threshold 0.5; window 9 (R=4).
// Identity: thr is monotone and the window contains the center, so
// reference output == (c > 0.5 && c == max9x9x9_raw(x)) ? c : 0.
static constexpr int Dd = 64;
static constexpr int Hh = 512;
static constexpr int Ww = 512;
static constexpr int RAD = 4;
static constexpr float THRESH_V = 0.5f;
static constexpr int W4 = Ww / 4;          // 128 float4 per row
static constexpr int PLANE4 = Hh * W4;     // 65536 float4 per D-plane

static constexpr int TH = 4;               // output h-rows per block
static constexpr int DC = 16;              // output d-planes per block
static constexpr int ROWS = TH + 2 * RAD;  // 12 staged rows per plane
static constexpr int STEPS = DC + 2 * RAD; // 24 d-steps per block
static constexpr int NBLK = (Hh / TH) * (Dd / DC);  // 512 blocks

__device__ __forceinline__ float4 f4max(float4 a, float4 b) {
    return make_float4(fmaxf(a.x, b.x), fmaxf(a.y, b.y), fmaxf(a.z, b.z), fmaxf(a.w, b.w));
}

__global__ __launch_bounds__(512, 4)
void fused_nms_k(const float4* __restrict__ x4, float4* __restrict__ o4) {
    // double-buffered staging of per-plane W-max rows: 2 * 12 * 128 * 16B = 48 KB
    __shared__ float4 buf[2][ROWS * W4];

    const int tid = threadIdx.x;
    const int w4  = tid & (W4 - 1);              // 0..127
    const int hr  = tid >> 7;                    // 0..3
    const int ht  = blockIdx.x & (Hh / TH - 1);  // 0..127
    const int dc  = blockIdx.x >> 7;             // 0..3
    const int h0  = ht * TH;
    const int d0  = dc * DC;

    const int colm = w4 ? w4 - 1 : 0;
    const int colp = (w4 < W4 - 1) ? w4 + 1 : W4 - 1;

    int rowoff[3];
#pragma unroll
    for (int k = 0; k < 3; ++k) {
        int gh = h0 - RAD + hr + 4 * k;
        gh = gh < 0 ? 0 : (gh > Hh - 1 ? Hh - 1 : gh);
        rowoff[k] = gh * W4;
    }
    const int outrow = (h0 + hr) * W4 + w4;

    const float4 z = make_float4(0.f, 0.f, 0.f, 0.f);
    float4 ring[9], xr[5];
#pragma unroll
    for (int i = 0; i < 9; ++i) ring[i] = z;
#pragma unroll
    for (int i = 0; i < 5; ++i) xr[i] = z;

    // load bank: 9 float4 for one plane (3 staged rows x {colm, w4, colp})
    float4 L[9];
    {
        int gd = d0 - RAD; gd = gd < 0 ? 0 : gd;
        const float4* pl = x4 + (size_t)gd * PLANE4;
#pragma unroll
        for (int k = 0; k < 3; ++k) {
            const float4* row = pl + rowoff[k];
            L[3 * k] = row[colm]; L[3 * k + 1] = row[w4]; L[3 * k + 2] = row[colp];
        }
    }

    for (int t = 0; t < STEPS; ++t) {
        float4* B = buf[t & 1];
        const float4 center = L[4];   // raw x at (gd(t), h0+hr, w4) — before overwrite

        // W-max of the 3 staged rows from the preloaded bank -> LDS
#pragma unroll
        for (int k = 0; k < 3; ++k) {
            float4 v0 = L[3 * k], v1 = L[3 * k + 1], v2 = L[3 * k + 2];
            float l3 = v0.w, l2 = fmaxf(v0.z, l3), l1 = fmaxf(v0.y, l2), l0 = fmaxf(v0.x, l1);
            float core = fmaxf(fmaxf(v1.x, v1.y), fmaxf(v1.z, v1.w));
            float r8 = v2.x, r9 = fmaxf(r8, v2.y), r10 = fmaxf(r9, v2.z), r11 = fmaxf(r10, v2.w);
            float4 o;
            o.x = fmaxf(l0, fmaxf(core, r8));
            o.y = fmaxf(l1, fmaxf(core, r9));
            o.z = fmaxf(l2, fmaxf(core, r10));
            o.w = fmaxf(l3, fmaxf(core, r11));
            B[k * 512 + tid] = o;
        }
        __syncthreads();

        // Prefetch plane t+1 AFTER the barrier (barrier drains vmcnt) so the
        // loads are in flight during the H-phase below; consumed next iter.
        if (t + 1 < STEPS) {
            int gd = d0 - RAD + t + 1;
            gd = gd < 0 ? 0 : (gd > Dd - 1 ? Dd - 1 : gd);
            const float4* pl = x4 + (size_t)gd * PLANE4;
#pragma unroll
            for (int k = 0; k < 3; ++k) {
                const float4* row = pl + rowoff[k];
                L[3 * k] = row[colm]; L[3 * k + 1] = row[w4]; L[3 * k + 2] = row[colp];
            }
        }

        // H-max over 9 staged rows at this thread's column
        float4 m = B[hr * W4 + w4];
#pragma unroll
        for (int i = 1; i < 9; ++i) m = f4max(m, B[(hr + i) * W4 + w4]);

        // push D-ring and center lag ring (static indices under unroll)
#pragma unroll
        for (int i = 0; i < 8; ++i) ring[i] = ring[i + 1];
        ring[8] = m;
#pragma unroll
        for (int i = 0; i < 4; ++i) xr[i] = xr[i + 1];
        xr[4] = center;

        if (t >= 2 * RAD) {           // ring holds planes d-4..d+4 (clamped)
            const int d = d0 + t - 2 * RAD;
            float4 mm = ring[0];
#pragma unroll
            for (int i = 1; i < 9; ++i) mm = f4max(mm, ring[i]);
            const float4 c = xr[0];   // raw center at plane d (lag 4)
            float4 q;
            q.x = (c.x > THRESH_V && c.x == mm.x) ? c.x : 0.0f;
            q.y = (c.y > THRESH_V && c.y == mm.y) ? c.y : 0.0f;
            q.z = (c.z > THRESH_V && c.z == mm.z) ? c.z : 0.0f;
            q.w = (c.w > THRESH_V && c.w == mm.w) ? c.w : 0.0f;
            o4[(size_t)d * PLANE4 + outrow] = q;
        }
    }
}

extern "C" void kernel_launch(void* const* d_in, const int* in_sizes, int n_in,
                              void* d_out, int out_size, void* d_ws, size_t ws_size,
                              hipStream_t stream) {
    const float4* x4 = (const float4*)d_in[0];
    float4* out4 = (float4*)d_out;
    (void)d_ws; (void)ws_size; (void)in_sizes; (void)n_in; (void)out_size;
    fused_nms_k<<<dim3(NBLK), dim3(512), 0, stream>>>(x4, out4);
}